// Round 5
// baseline (171.860 us; speedup 1.0000x reference)
//
#include <hip/hip_runtime.h>

typedef unsigned short u16;
typedef short bf16x8 __attribute__((ext_vector_type(8)));
typedef float f32x4 __attribute__((ext_vector_type(4)));
typedef u16 u16x8 __attribute__((ext_vector_type(8)));
typedef u16 u16x4 __attribute__((ext_vector_type(4)));

#define B_ 4
#define S_ 4096
#define E_ 1024
#define H_ 16
#define D_ 64
#define M_ 16384
#define N_ 3072
#define K_ 1024

__device__ __forceinline__ u16 f2b(float f) {
    unsigned x = __builtin_bit_cast(unsigned, f);
    return (u16)((x + 0x7fffu + ((x >> 16) & 1u)) >> 16);   // RNE
}
__device__ __forceinline__ float b2f(u16 u) {
    unsigned x = ((unsigned)u) << 16;
    return __builtin_bit_cast(float, x);
}
__device__ __forceinline__ float phi_f(float x) { return x > 0.f ? x + 1.f : __expf(x); }

__device__ __forceinline__ void gload16(const void* g, void* l) {
    __builtin_amdgcn_global_load_lds((const __attribute__((address_space(1))) void*)g,
                                     (__attribute__((address_space(3))) void*)l, 16, 0, 0);
}

#define MEMFENCE asm volatile("" ::: "memory")

// ---------------- kernel 1: fp32 -> bf16 convert ----------------
__global__ void cvt_bf16(const float* __restrict__ in, u16* __restrict__ out, int n8) {
    int stride = gridDim.x * blockDim.x;
    for (int i = blockIdx.x * blockDim.x + threadIdx.x; i < n8; i += stride) {
        const float4* p = (const float4*)(in + (size_t)i * 8);
        float4 a = p[0], b = p[1];
        u16x8 o;
        o[0] = f2b(a.x); o[1] = f2b(a.y); o[2] = f2b(a.z); o[3] = f2b(a.w);
        o[4] = f2b(b.x); o[5] = f2b(b.y); o[6] = f2b(b.z); o[7] = f2b(b.w);
        *(u16x8*)(out + (size_t)i * 8) = o;
    }
}

// ---------------- kernel 2: QKV GEMM, 256^2 tile, true 8-phase pipeline ----------------
// Phase body: { RD(this phase's MM frags); ST(sched); [vmcnt(4) @Ph4/Ph8];
//               BAR; lgkmcnt(0)+sched_barrier; 16xMFMA }.
// MM issues at phase end -> MFMA pipe drains while next phase's ds_reads/stage/
// barrier run (LDS||MFMA overlap). vmcnt gate BEFORE barrier + read AFTER it
// gives cross-wave staging visibility (per-wave vmcnt alone is not enough).
//
// RD phases (tile t buf0, t+1 buf1): Ph1: A-lo(t)+b01(t) [12 reads]; Ph2: b23 [4];
// Ph3: A-hi [8]; Ph4: none; Ph5: A-lo(t+1)+b01(t+1) [12]; Ph6: b23 [4];
// Ph7: A-hi [8]; Ph8: none.  (24 reads/tile, no re-reads; b01/b23/av persist.)
// ST schedule (constraint: region's last RD phase <= Phi-2):
//   Ph1: buf1 A-hi(t+1)  [RD Ph7-prev]     Ph5: buf0 A-hi(t+2)  [RD Ph3]
//   Ph2: buf1 B-h2(t+1)  [RD Ph6-prev]     Ph6: buf0 B-h2(t+2)  [RD Ph2]
//   Ph3: buf0 A-lo(t+2)  [RD Ph1]          Ph7: buf1 A-lo(t+3)  [RD Ph5]
//   Ph4: buf0 B-h1(t+2)  [RD Ph1,2]        Ph8: buf1 B-h1(t+3)  [RD Ph5,6]
// vmcnt(4)@Ph4 (leaves Ph3,Ph4 STs) gates buf1(t+1) reads at Ph5+;
// vmcnt(4)@Ph8 (leaves Ph7,Ph8 STs) gates buf0(t+2) reads at Ph1-next+.

__global__ __launch_bounds__(512, 2) void gemm_qkv(
    const u16* __restrict__ Abf, const u16* __restrict__ Wbf,
    const float* __restrict__ bias, const float* __restrict__ mask,
    u16* __restrict__ KQ, u16* __restrict__ KKT, u16* __restrict__ VT)
{
    __shared__ __align__(16) char lds[131072];   // buf0: A 32K | B 32K ; buf1 same

    int wg  = blockIdx.x;
    int xcd = wg & 7, ii = wg >> 3;        // 768 % 8 == 0 -> bijective
    int tm  = xcd * 8 + ii / 12;
    int tn  = ii % 12;
    int m0 = tm << 8, n0 = tn << 8;

    int t = threadIdx.x;
    int l = t & 63, wid = t >> 6;
    int wr = wid >> 2, wc = wid & 3;       // 2 x 4 waves, per-wave C = 128x64
    int lg = l >> 4, lr = l & 15;

    int srow  = t >> 3;                    // 0..63 (row within 64-row chunk)
    int scolE = ((t & 7) ^ (srow & 7)) << 3;   // pre-swizzled source granule
    int t16   = t * 16;

    const u16* gA = Abf + (size_t)(m0 + srow) * K_ + scolE;
    const u16* gB = Wbf + (size_t)(n0 + srow) * K_ + scolE;

    const char* aB = lds + (wr * 128 + lr) * 128;
    const char* bB = lds + 32768 + (wc * 64 + lr) * 128;
    int pc0 = (lg * 16) ^ ((lr & 7) << 4);
    int pc1 = pc0 ^ 64;

    f32x4 acc[8][4] = {};
    bf16x8 av[4][2], b01[2][2], b23[2][2];

#define RD_A(BO, MI0) { _Pragma("unroll") for (int m_ = 0; m_ < 4; ++m_) { \
    av[m_][0] = *(const bf16x8*)(aB + (BO) + (MI0 + m_) * 2048 + pc0); \
    av[m_][1] = *(const bf16x8*)(aB + (BO) + (MI0 + m_) * 2048 + pc1); } }

#define RD_B01(BO) { _Pragma("unroll") for (int n_ = 0; n_ < 2; ++n_) { \
    b01[n_][0] = *(const bf16x8*)(bB + (BO) + n_ * 2048 + pc0); \
    b01[n_][1] = *(const bf16x8*)(bB + (BO) + n_ * 2048 + pc1); } }

#define RD_B23(BO) { _Pragma("unroll") for (int n_ = 0; n_ < 2; ++n_) { \
    b23[n_][0] = *(const bf16x8*)(bB + (BO) + (2 + n_) * 2048 + pc0); \
    b23[n_][1] = *(const bf16x8*)(bB + (BO) + (2 + n_) * 2048 + pc1); } }

    // A chunks: HI=0 -> rows 0-63 & 128-191 (chunks 0,2 = per-wave mi 0-3);
    //           HI=1 -> rows 64-127 & 192-255 (chunks 1,3 = per-wave mi 4-7)
#define ST_A(TT, HI, BO) { \
    gload16(gA + (size_t)((HI) * 64) * K_ + (TT) * 64, lds + (BO) + (HI) * 8192 + t16); \
    gload16(gA + (size_t)((HI) * 64 + 128) * K_ + (TT) * 64, lds + (BO) + 16384 + (HI) * 8192 + t16); }

    // B half PR: N-rows PR*128 .. PR*128+127 (chunks 2PR, 2PR+1)
#define ST_B(TT, PR, BO) { \
    gload16(gB + (size_t)((PR) * 128) * K_ + (TT) * 64, lds + (BO) + 32768 + (PR) * 16384 + t16); \
    gload16(gB + (size_t)((PR) * 128 + 64) * K_ + (TT) * 64, lds + (BO) + 32768 + (PR) * 16384 + 8192 + t16); }

#define BAR { MEMFENCE; __builtin_amdgcn_s_barrier(); MEMFENCE; }
#define LGKM0 { asm volatile("s_waitcnt lgkmcnt(0)" ::: "memory"); \
                __builtin_amdgcn_sched_barrier(0); }

#define MM16(MI0, NI0, BV) { __builtin_amdgcn_s_setprio(1); \
    _Pragma("unroll") for (int m_ = 0; m_ < 4; ++m_) \
    _Pragma("unroll") for (int n_ = 0; n_ < 2; ++n_) \
    _Pragma("unroll") for (int h_ = 0; h_ < 2; ++h_) \
        acc[(MI0) + m_][(NI0) + n_] = __builtin_amdgcn_mfma_f32_16x16x32_bf16( \
            av[m_][h_], BV[n_][h_], acc[(MI0) + m_][(NI0) + n_], 0, 0, 0); \
    __builtin_amdgcn_s_setprio(0); }

    // prologue: buf0(0) complete (8 gloads), then buf1(1) A-lo + B-h1 (4)
    ST_A(0, 0, 0); ST_B(0, 0, 0); ST_B(0, 1, 0); ST_A(0, 1, 0);
    ST_A(1, 0, 65536); ST_B(1, 0, 65536);
    asm volatile("s_waitcnt vmcnt(4)" ::: "memory");   // buf0 landed; buf1 4 in flight
    __builtin_amdgcn_s_barrier();
    MEMFENCE;

#pragma unroll 1
    for (int kt = 0; kt < 16; kt += 2) {
        int tp2 = kt + 2 < 16 ? kt + 2 : 15;   // junk-clamp: same positional invariant
        int tp3 = kt + 3 < 16 ? kt + 3 : 15;
        // Ph1
        RD_A(0, 0); RD_B01(0); ST_A(kt + 1, 1, 65536);
        BAR; LGKM0; MM16(0, 0, b01);
        // Ph2
        RD_B23(0); ST_B(kt + 1, 1, 65536);
        BAR; LGKM0; MM16(0, 2, b23);
        // Ph3
        RD_A(0, 4); ST_A(tp2, 0, 0);
        BAR; LGKM0; MM16(4, 2, b23);
        // Ph4 (no RD)
        ST_B(tp2, 0, 0);
        asm volatile("s_waitcnt vmcnt(4)" ::: "memory");
        BAR; LGKM0; MM16(4, 0, b01);
        // Ph5
        RD_A(65536, 0); RD_B01(65536); ST_A(tp2, 1, 0);
        BAR; LGKM0; MM16(0, 0, b01);
        // Ph6
        RD_B23(65536); ST_B(tp2, 1, 0);
        BAR; LGKM0; MM16(0, 2, b23);
        // Ph7
        RD_A(65536, 4); ST_A(tp3, 0, 65536);
        BAR; LGKM0; MM16(4, 2, b23);
        // Ph8 (no RD)
        ST_B(tp3, 0, 65536);
        asm volatile("s_waitcnt vmcnt(4)" ::: "memory");
        BAR; LGKM0; MM16(4, 0, b01);
    }

    // ---------------- epilogue: bias + phi/mask + store ----------------
    int part = n0 >> 10;   // 0=q 1=k 2=v

    float bv[4];
#pragma unroll
    for (int ni = 0; ni < 4; ++ni) bv[ni] = bias[n0 + wc * 64 + ni * 16 + lr];

    if (part == 0) {
#pragma unroll
        for (int mi = 0; mi < 8; ++mi)
#pragma unroll
            for (int j = 0; j < 4; ++j) {
                int row = m0 + wr * 128 + mi * 16 + lg * 4 + j;
#pragma unroll
                for (int ni = 0; ni < 4; ++ni) {
                    int col = n0 + wc * 64 + ni * 16 + lr;
                    KQ[(size_t)row * E_ + col] = f2b(phi_f(acc[mi][ni][j] + bv[ni]));
                }
            }
    } else {
        u16* dst0 = (part == 1) ? KKT : VT;
        int b  = m0 >> 12;
        int sl = m0 & (S_ - 1);
        int h  = ((tn & 3) << 2) | wc;
#pragma unroll
        for (int mi = 0; mi < 8; ++mi) {
            int sbase = sl + wr * 128 + mi * 16 + lg * 4;
            float mk[4];
#pragma unroll
            for (int j = 0; j < 4; ++j)
                mk[j] = (part == 1) ? mask[m0 + wr * 128 + mi * 16 + lg * 4 + j] : 1.f;
#pragma unroll
            for (int ni = 0; ni < 4; ++ni) {
                u16x4 o;
#pragma unroll
                for (int j = 0; j < 4; ++j) {
                    float v = acc[mi][ni][j] + bv[ni];
                    if (part == 1) v = phi_f(v * mk[j]);
                    o[j] = f2b(v);
                }
                int d = ni * 16 + lr;
                *(u16x4*)(dst0 + ((size_t)((b * H_ + h) * D_ + d)) * S_ + sbase) = o;
            }
        }
    }
}

// ---------------- kernel 3: kv + ksum partials over s-chunks ----------------
__global__ __launch_bounds__(256) void kv_ksum_partial(
    const u16* __restrict__ VT, const u16* __restrict__ KKT,
    float* __restrict__ KVP, float* __restrict__ KSP)
{
    __shared__ __align__(16) u16 smem[8192];   // As 4096 | Bs 4096
    u16* As = smem;
    u16* Bs = smem + 4096;
    int bh = blockIdx.x;
    int ch = blockIdx.y;
    int s0 = ch << 8;
    int t = threadIdx.x;
    int l = t & 63, w = t >> 6;
    int lg = l >> 4, lr = l & 15;
    const u16* Ag = VT + (size_t)bh * (D_ * S_);
    const u16* Bg = KKT + (size_t)bh * (D_ * S_);
    int srow = t >> 3, scol = (t & 7) << 3;

    f32x4 acc[4] = {};
    float ks = 0.f;
    int kd = t >> 2;
    int kq4 = (t & 3) << 4;

    for (int kt = 0; kt < 4; ++kt) {
        __syncthreads();
        int sb = s0 + kt * 64;
#pragma unroll
        for (int i = 0; i < 2; ++i) {
            gload16(Ag + (size_t)(srow + i * 32) * S_ + sb + scol, As + i * 2048 + t * 8);
            gload16(Bg + (size_t)(srow + i * 32) * S_ + sb + scol, Bs + i * 2048 + t * 8);
        }
        __syncthreads();
#pragma unroll
        for (int i = 0; i < 16; ++i) ks += b2f(Bs[kd * 64 + kq4 + i]);
#pragma unroll
        for (int kh = 0; kh < 2; ++kh) {
            int ko = kh * 32 + lg * 8;
            bf16x8 a = *(const bf16x8*)&As[(w * 16 + lr) * 64 + ko];
#pragma unroll
            for (int ni = 0; ni < 4; ++ni) {
                bf16x8 bb = *(const bf16x8*)&Bs[(ni * 16 + lr) * 64 + ko];
                acc[ni] = __builtin_amdgcn_mfma_f32_16x16x32_bf16(a, bb, acc[ni], 0, 0, 0);
            }
        }
    }
    float* kvp = KVP + (size_t)ch * (64 * 4096) + bh * 4096;
#pragma unroll
    for (int ni = 0; ni < 4; ++ni)
#pragma unroll
        for (int j = 0; j < 4; ++j)
            kvp[(w * 16 + lg * 4 + j) * 64 + ni * 16 + lr] = acc[ni][j];
    ks += __shfl_xor(ks, 1);
    ks += __shfl_xor(ks, 2);
    if ((t & 3) == 0) KSP[ch * 4096 + bh * 64 + kd] = ks;
}

// ---------------- kernel 4: deterministic partial reduce ----------------
__global__ void reduce_kv(const float* __restrict__ KVP, const float* __restrict__ KSP,
                          float* __restrict__ KV, float* __restrict__ KSUM)
{
    int g = blockIdx.x * 256 + threadIdx.x;   // 65536 threads
#pragma unroll 1
    for (int i = g * 4; i < g * 4 + 4; ++i) {
        float s = 0.f;
#pragma unroll
        for (int c = 0; c < 16; ++c) s += KVP[(size_t)c * (64 * 4096) + i];
        KV[i] = s;
    }
    if (g < 4096) {
        float s = 0.f;
#pragma unroll
        for (int c = 0; c < 16; ++c) s += KSP[c * 4096 + g];
        KSUM[g] = s;
    }
}

// ---------------- kernel 5: attn = kq·[kv;ksum] , divide by den ----------------
__global__ __launch_bounds__(256) void attn_out(
    const u16* __restrict__ KQ, const float* __restrict__ KV,
    const float* __restrict__ KSUM, float* __restrict__ Out)
{
    __shared__ __align__(16) u16 kqs[16384];   // 256 x 64 bf16 (32 KB)
    __shared__ __align__(16) u16 bsm[5120];    // 80 x 64 bf16
    __shared__ float den[256];
    int bh = blockIdx.x, ch = blockIdx.y;
    int b = bh >> 4, h = bh & 15;
    int t = threadIdx.x;
    int l = t & 63, w = t >> 6;
    int lg = l >> 4, lr = l & 15;
    size_t row0 = (size_t)b * S_ + ch * 256;
    int srow = t >> 3, scol = (t & 7) << 3;
#pragma unroll
    for (int i = 0; i < 8; ++i)
        gload16(KQ + (row0 + srow + i * 32) * E_ + h * 64 + scol, kqs + i * 2048 + t * 8);

    const float* kvg = KV + bh * 4096;
#pragma unroll
    for (int ii = 0; ii < 16; ii += 4) {
        float4 v = *(const float4*)(kvg + t * 16 + ii);
        u16x4 o; o[0] = f2b(v.x); o[1] = f2b(v.y); o[2] = f2b(v.z); o[3] = f2b(v.w);
        *(u16x4*)&bsm[t * 16 + ii] = o;
    }
    if (t < 64) bsm[4096 + t] = f2b(KSUM[bh * 64 + t]);
    for (int i = t; i < 960; i += 256) bsm[4160 + i] = 0;
    __syncthreads();

    f32x4 acc[4][5] = {};
#pragma unroll
    for (int kh = 0; kh < 2; ++kh) {
        int ko = kh * 32 + lg * 8;
        bf16x8 af[4];
#pragma unroll
        for (int mi = 0; mi < 4; ++mi)
            af[mi] = *(const bf16x8*)&kqs[(w * 64 + mi * 16 + lr) * 64 + ko];
#pragma unroll
        for (int ni = 0; ni < 5; ++ni) {
            bf16x8 bb = *(const bf16x8*)&bsm[(ni * 16 + lr) * 64 + ko];
#pragma unroll
            for (int mi = 0; mi < 4; ++mi)
                acc[mi][ni] = __builtin_amdgcn_mfma_f32_16x16x32_bf16(af[mi], bb, acc[mi][ni], 0, 0, 0);
        }
    }
    if (lr == 0) {
#pragma unroll
        for (int mi = 0; mi < 4; ++mi)
#pragma unroll
            for (int j = 0; j < 4; ++j)
                den[w * 64 + mi * 16 + lg * 4 + j] = acc[mi][4][j];
    }
    __syncthreads();
#pragma unroll
    for (int mi = 0; mi < 4; ++mi)
#pragma unroll
        for (int j = 0; j < 4; ++j) {
            int sl = w * 64 + mi * 16 + lg * 4 + j;
            float z = 1.f / (den[sl] + 1e-6f);
            float* op = Out + (row0 + sl) * E_ + h * 64;
#pragma unroll
            for (int ni = 0; ni < 4; ++ni)
                op[ni * 16 + lr] = acc[mi][ni][j] * z;
        }
}

extern "C" void kernel_launch(void* const* d_in, const int* in_sizes, int n_in,
                              void* d_out, int out_size, void* d_ws, size_t ws_size,
                              hipStream_t stream)
{
    const float* inputs = (const float*)d_in[0];
    const float* mask   = (const float*)d_in[1];
    const float* w_qkv  = (const float*)d_in[2];
    const float* b_qkv  = (const float*)d_in[3];

    u16* Abf = (u16*)d_ws;                      // 16777216 bf16
    u16* Wbf = Abf + (size_t)M_ * K_;           // 3145728 bf16
    u16* KQ  = Wbf + (size_t)N_ * K_;           // 16777216 bf16
    float* KVP  = (float*)(KQ + (size_t)M_ * E_);   // 16*262144 f32
    float* KSP  = KVP + 16 * 64 * 4096;             // 16*4096 f32
    float* KV   = KSP + 16 * 4096;                  // 262144 f32
    float* KSUM = KV + 64 * 4096;                   // 4096 f32

    u16* KKT = (u16*)d_out;
    u16* VT  = KKT + (size_t)M_ * E_;

    cvt_bf16<<<2048, 256, 0, stream>>>(inputs, Abf, M_ * K_ / 8);
    cvt_bf16<<<768, 256, 0, stream>>>(w_qkv, Wbf, N_ * K_ / 8);
    gemm_qkv<<<768, 512, 0, stream>>>(Abf, Wbf, b_qkv, mask, KQ, KKT, VT);
    kv_ksum_partial<<<dim3(64, 16), 256, 0, stream>>>(VT, KKT, KVP, KSP);
    reduce_kv<<<256, 256, 0, stream>>>(KVP, KSP, KV, KSUM);
    attn_out<<<dim3(64, 16), 256, 0, stream>>>(KQ, KV, KSUM, (float*)d_out);
}

// Round 6
// 156.168 us; speedup vs baseline: 1.1005x; 1.1005x over previous
//
#include <hip/hip_runtime.h>

typedef unsigned short u16;
typedef short bf16x8 __attribute__((ext_vector_type(8)));
typedef float f32x4 __attribute__((ext_vector_type(4)));
typedef u16 u16x8 __attribute__((ext_vector_type(8)));
typedef u16 u16x4 __attribute__((ext_vector_type(4)));

#define B_ 4
#define S_ 4096
#define E_ 1024
#define H_ 16
#define D_ 64
#define M_ 16384
#define N_ 3072
#define K_ 1024

__device__ __forceinline__ u16 f2b(float f) {
    unsigned x = __builtin_bit_cast(unsigned, f);
    return (u16)((x + 0x7fffu + ((x >> 16) & 1u)) >> 16);   // RNE
}
__device__ __forceinline__ float b2f(u16 u) {
    unsigned x = ((unsigned)u) << 16;
    return __builtin_bit_cast(float, x);
}
__device__ __forceinline__ float phi_f(float x) { return x > 0.f ? x + 1.f : __expf(x); }

__device__ __forceinline__ void gload16(const void* g, void* l) {
    __builtin_amdgcn_global_load_lds((const __attribute__((address_space(1))) void*)g,
                                     (__attribute__((address_space(3))) void*)l, 16, 0, 0);
}

#define MEMFENCE asm volatile("" ::: "memory")
#define BAR { MEMFENCE; __builtin_amdgcn_s_barrier(); MEMFENCE; }
#define LGKM0 { asm volatile("s_waitcnt lgkmcnt(0)" ::: "memory"); \
                __builtin_amdgcn_sched_barrier(0); }
#define VMCNT(n) asm volatile("s_waitcnt vmcnt(" #n ")" ::: "memory")

// ---------------- kernel 1: fp32 -> bf16 convert ----------------
__global__ void cvt_bf16(const float* __restrict__ in, u16* __restrict__ out, int n8) {
    int stride = gridDim.x * blockDim.x;
    for (int i = blockIdx.x * blockDim.x + threadIdx.x; i < n8; i += stride) {
        const float4* p = (const float4*)(in + (size_t)i * 8);
        float4 a = p[0], b = p[1];
        u16x8 o;
        o[0] = f2b(a.x); o[1] = f2b(a.y); o[2] = f2b(a.z); o[3] = f2b(a.w);
        o[4] = f2b(b.x); o[5] = f2b(b.y); o[6] = f2b(b.z); o[7] = f2b(b.w);
        *(u16x8*)(out + (size_t)i * 8) = o;
    }
}

// ---------------- fused QKV GEMM + in-block kv/ksum partials ----------------
// Block (tm, g): s-rows tm*256..+255, heads g*4..g*4+3. Tiles: V -> K -> Q with
// the R5 8-phase pipeline (drained between tiles).  After K-tile, kk (phi'd,
// masked) is written to LDS [head][d=64][s=256] bf16 with ((d&7)<<4) XOR
// swizzle; V is read back from VT (written by THIS block -> self-contained,
// L2-hot) and a small MFMA produces kv[h][m][d] + ksum[h][d] partials.
// KKT never exists in HBM; kv_ksum kernel deleted.

#define RD_A(BO, MI0) { _Pragma("unroll") for (int m_ = 0; m_ < 4; ++m_) { \
    av[m_][0] = *(const bf16x8*)(aB + (BO) + (MI0 + m_) * 2048 + pc0); \
    av[m_][1] = *(const bf16x8*)(aB + (BO) + (MI0 + m_) * 2048 + pc1); } }

#define RD_B01(BO) { _Pragma("unroll") for (int n_ = 0; n_ < 2; ++n_) { \
    b01[n_][0] = *(const bf16x8*)(bB + (BO) + n_ * 2048 + pc0); \
    b01[n_][1] = *(const bf16x8*)(bB + (BO) + n_ * 2048 + pc1); } }

#define RD_B23(BO) { _Pragma("unroll") for (int n_ = 0; n_ < 2; ++n_) { \
    b23[n_][0] = *(const bf16x8*)(bB + (BO) + (2 + n_) * 2048 + pc0); \
    b23[n_][1] = *(const bf16x8*)(bB + (BO) + (2 + n_) * 2048 + pc1); } }

#define ST_A(TT, HI, BO) { \
    gload16(gA + (size_t)((HI) * 64) * K_ + (TT) * 64, lds + (BO) + (HI) * 8192 + t16); \
    gload16(gA + (size_t)((HI) * 64 + 128) * K_ + (TT) * 64, lds + (BO) + 16384 + (HI) * 8192 + t16); }

#define ST_B(TT, PR, BO) { \
    gload16(gB + (size_t)((PR) * 128) * K_ + (TT) * 64, lds + (BO) + 32768 + (PR) * 16384 + t16); \
    gload16(gB + (size_t)((PR) * 128 + 64) * K_ + (TT) * 64, lds + (BO) + 32768 + (PR) * 16384 + 8192 + t16); }

#define MM16(MI0, NI0, BV) { __builtin_amdgcn_s_setprio(1); \
    _Pragma("unroll") for (int m_ = 0; m_ < 4; ++m_) \
    _Pragma("unroll") for (int n_ = 0; n_ < 2; ++n_) \
    _Pragma("unroll") for (int h_ = 0; h_ < 2; ++h_) \
        acc[(MI0) + m_][(NI0) + n_] = __builtin_amdgcn_mfma_f32_16x16x32_bf16( \
            av[m_][h_], BV[n_][h_], acc[(MI0) + m_][(NI0) + n_], 0, 0, 0); \
    __builtin_amdgcn_s_setprio(0); }

__device__ __forceinline__ void run_tile(
    const u16* gA, const u16* gB, char* lds, int t16,
    const char* aB, const char* bB, int pc0, int pc1, f32x4 (&acc)[8][4])
{
    bf16x8 av[4][2], b01[2][2], b23[2][2];
    // prologue: tile0 full -> buf0; tile1 A-lo + B-h1 -> buf1
    ST_A(0, 0, 0); ST_B(0, 0, 0); ST_B(0, 1, 0); ST_A(0, 1, 0);
    ST_A(1, 0, 65536); ST_B(1, 0, 65536);
    VMCNT(4);                 // tile0's 8 oldest done (vmcnt waits oldest-first)
    __builtin_amdgcn_s_barrier();
    MEMFENCE;
#pragma unroll 1
    for (int kt = 0; kt < 16; kt += 2) {
        int tp2 = kt + 2 < 16 ? kt + 2 : 15;   // junk-clamp, positionally safe
        int tp3 = kt + 3 < 16 ? kt + 3 : 15;
        RD_A(0, 0); RD_B01(0); ST_A(kt + 1, 1, 65536); BAR; LGKM0; MM16(0, 0, b01);
        RD_B23(0);  ST_B(kt + 1, 1, 65536);            BAR; LGKM0; MM16(0, 2, b23);
        RD_A(0, 4); ST_A(tp2, 0, 0);                   BAR; LGKM0; MM16(4, 2, b23);
        ST_B(tp2, 0, 0); VMCNT(4);                     BAR; LGKM0; MM16(4, 0, b01);
        RD_A(65536, 0); RD_B01(65536); ST_A(tp2, 1, 0); BAR; LGKM0; MM16(0, 0, b01);
        RD_B23(65536);  ST_B(tp2, 1, 0);                BAR; LGKM0; MM16(0, 2, b23);
        RD_A(65536, 4); ST_A(tp3, 0, 65536);            BAR; LGKM0; MM16(4, 2, b23);
        ST_B(tp3, 0, 65536); VMCNT(4);                  BAR; LGKM0; MM16(4, 0, b01);
    }
    VMCNT(0);                 // drain (junk prefetches target LDS; must land
    __builtin_amdgcn_s_barrier();   //  before LDS is repurposed/re-staged)
    MEMFENCE;
}

__global__ __launch_bounds__(512, 2) void gemm_fused(
    const u16* __restrict__ Abf, const u16* __restrict__ Wbf,
    const float* __restrict__ bias, const float* __restrict__ mask,
    u16* __restrict__ KQ, u16* VT,
    float* __restrict__ KVP, float* __restrict__ KSP)
{
    __shared__ __align__(16) char lds[131072];

    int wg  = blockIdx.x;                 // 256 blocks, 1/CU
    int xcd = wg & 7, ii = wg >> 3;       // 32 blocks per XCD
    int tm  = xcd * 8 + (ii >> 2);        // 0..63: s-strip (A-panel L2 reuse)
    int g   = ii & 3;                     // head-group 0..3
    int m0  = tm << 8;
    int b   = tm >> 4;
    int s0  = (tm & 15) << 8;             // s_local base

    int t = threadIdx.x;
    int l = t & 63, wid = t >> 6;
    int wr = wid >> 2, wc = wid & 3;      // 2 x 4 waves, per-wave C = 128x64
    int lg = l >> 4, lr = l & 15;

    int srow  = t >> 3;
    int scolE = ((t & 7) ^ (srow & 7)) << 3;   // pre-swizzled source (T2/m173)
    int t16   = t * 16;

    const u16* gA = Abf + (size_t)(m0 + srow) * K_ + scolE;
    const char* aB = lds + (wr * 128 + lr) * 128;
    const char* bB = lds + 32768 + (wc * 64 + lr) * 128;
    int pc0 = (lg * 16) ^ ((lr & 7) << 4);
    int pc1 = pc0 ^ 64;

    // ================= tile V (n0 = 2048 + g*256) =================
    {
        int n0 = 2048 + g * 256;
        const u16* gB = Wbf + (size_t)(n0 + srow) * K_ + scolE;
        f32x4 acc[8][4] = {};
        run_tile(gA, gB, lds, t16, aB, bB, pc0, pc1, acc);
        float bv[4];
#pragma unroll
        for (int ni = 0; ni < 4; ++ni) bv[ni] = bias[n0 + wc * 64 + ni * 16 + lr];
        int h = g * 4 + wc;
#pragma unroll
        for (int mi = 0; mi < 8; ++mi) {
            int sbase = s0 + wr * 128 + mi * 16 + lg * 4;
#pragma unroll
            for (int ni = 0; ni < 4; ++ni) {
                u16x4 o;
#pragma unroll
                for (int j = 0; j < 4; ++j) o[j] = f2b(acc[mi][ni][j] + bv[ni]);
                int d = ni * 16 + lr;
                *(u16x4*)(VT + ((size_t)((b * H_ + h) * D_ + d)) * S_ + sbase) = o;
            }
        }
    }

    // ================= tile K (n0 = 1024 + g*256) -> kk in LDS =================
    {
        int n0 = 1024 + g * 256;
        const u16* gB = Wbf + (size_t)(n0 + srow) * K_ + scolE;
        f32x4 acc[8][4] = {};
        run_tile(gA, gB, lds, t16, aB, bB, pc0, pc1, acc);
        float bv[4];
#pragma unroll
        for (int ni = 0; ni < 4; ++ni) bv[ni] = bias[n0 + wc * 64 + ni * 16 + lr];
        // run_tile drained (vmcnt0 + barrier) -> LDS free: write kk
        // layout: [head=wc][d][s] bf16, byte = wc*32768 + d*512 + (s*2 ^ ((d&7)<<4))
#pragma unroll
        for (int mi = 0; mi < 8; ++mi) {
            int sl0 = wr * 128 + mi * 16 + lg * 4;
            float mk[4];
#pragma unroll
            for (int j = 0; j < 4; ++j) mk[j] = mask[m0 + sl0 + j];
#pragma unroll
            for (int ni = 0; ni < 4; ++ni) {
                int d = ni * 16 + lr;
                u16x4 o;
#pragma unroll
                for (int j = 0; j < 4; ++j)
                    o[j] = f2b(phi_f((acc[mi][ni][j] + bv[ni]) * mk[j]));
                *(u16x4*)(lds + wc * 32768 + d * 512 + ((sl0 * 2) ^ ((d & 7) << 4))) = o;
            }
        }
    }
    __syncthreads();

    // ================= kv + ksum partials (kk from LDS, v from VT) =================
    {
        int head = wid & 3, mh = wid >> 2;          // wave -> (head, m-half)
        int bh = b * 16 + g * 4 + head;
        f32x4 akv[2][4] = {};
        const u16* vbase = VT + ((size_t)(bh * 64 + mh * 32 + lr)) * S_ + s0;
#pragma unroll
        for (int ks = 0; ks < 8; ++ks) {
            bf16x8 vf[2];
#pragma unroll
            for (int mi = 0; mi < 2; ++mi)
                vf[mi] = *(const bf16x8*)(vbase + (size_t)mi * 16 * S_ + ks * 32 + lg * 8);
#pragma unroll
            for (int ni = 0; ni < 4; ++ni) {
                int dd = ni * 16 + lr;
                bf16x8 kf = *(const bf16x8*)(lds + head * 32768 + dd * 512 +
                                             ((ks * 64 + lg * 16) ^ ((dd & 7) << 4)));
                akv[0][ni] = __builtin_amdgcn_mfma_f32_16x16x32_bf16(vf[0], kf, akv[0][ni], 0, 0, 0);
                akv[1][ni] = __builtin_amdgcn_mfma_f32_16x16x32_bf16(vf[1], kf, akv[1][ni], 0, 0, 0);
            }
        }
        float* kvp = KVP + ((size_t)(tm & 15) * 64 + bh) * 4096;
#pragma unroll
        for (int mi = 0; mi < 2; ++mi)
#pragma unroll
            for (int ni = 0; ni < 4; ++ni)
#pragma unroll
                for (int j = 0; j < 4; ++j)
                    kvp[(mh * 32 + mi * 16 + lg * 4 + j) * 64 + ni * 16 + lr] = akv[mi][ni][j];
        // ksum[h][d] = sum_s kk: 512 threads = 4h x 64d x 2 s-halves
        int hd = t >> 7, dd2 = (t >> 1) & 63, hf = t & 1;
        float ksm = 0.f;
#pragma unroll
        for (int i = 0; i < 16; ++i) {
            bf16x8 kk8 = *(const bf16x8*)(lds + hd * 32768 + dd2 * 512 +
                                          ((hf * 256 + i * 16) ^ ((dd2 & 7) << 4)));
#pragma unroll
            for (int e = 0; e < 8; ++e) ksm += b2f((u16)kk8[e]);
        }
        ksm += __shfl_xor(ksm, 1);
        if (!hf) KSP[(tm & 15) * 4096 + (b * 16 + g * 4 + hd) * 64 + dd2] = ksm;
    }
    __syncthreads();

    // ================= tile Q (n0 = g*256) =================
    {
        int n0 = g * 256;
        const u16* gB = Wbf + (size_t)(n0 + srow) * K_ + scolE;
        f32x4 acc[8][4] = {};
        run_tile(gA, gB, lds, t16, aB, bB, pc0, pc1, acc);
        float bv[4];
#pragma unroll
        for (int ni = 0; ni < 4; ++ni) bv[ni] = bias[n0 + wc * 64 + ni * 16 + lr];
#pragma unroll
        for (int mi = 0; mi < 8; ++mi)
#pragma unroll
            for (int j = 0; j < 4; ++j) {
                int row = m0 + wr * 128 + mi * 16 + lg * 4 + j;
#pragma unroll
                for (int ni = 0; ni < 4; ++ni) {
                    int col = n0 + wc * 64 + ni * 16 + lr;
                    KQ[(size_t)row * E_ + col] = f2b(phi_f(acc[mi][ni][j] + bv[ni]));
                }
            }
    }
}

// ---------------- deterministic partial reduce ----------------
__global__ void reduce_kv(const float* __restrict__ KVP, const float* __restrict__ KSP,
                          float* __restrict__ KV, float* __restrict__ KSUM)
{
    int g = blockIdx.x * 256 + threadIdx.x;   // 65536 threads
#pragma unroll 1
    for (int i = g * 4; i < g * 4 + 4; ++i) {
        float s = 0.f;
#pragma unroll
        for (int c = 0; c < 16; ++c) s += KVP[(size_t)c * (64 * 4096) + i];
        KV[i] = s;
    }
    if (g < 4096) {
        float s = 0.f;
#pragma unroll
        for (int c = 0; c < 16; ++c) s += KSP[c * 4096 + g];
        KSUM[g] = s;
    }
}

// ---------------- attn = kq·[kv;ksum] , divide by den ----------------
__global__ __launch_bounds__(256) void attn_out(
    const u16* __restrict__ KQ, const float* __restrict__ KV,
    const float* __restrict__ KSUM, float* __restrict__ Out)
{
    __shared__ __align__(16) u16 kqs[16384];   // 256 x 64 bf16 (32 KB)
    __shared__ __align__(16) u16 bsm[5120];    // 80 x 64 bf16
    __shared__ float den[256];
    int bh = blockIdx.x, ch = blockIdx.y;
    int b = bh >> 4, h = bh & 15;
    int t = threadIdx.x;
    int l = t & 63, w = t >> 6;
    int lg = l >> 4, lr = l & 15;
    size_t row0 = (size_t)b * S_ + ch * 256;
    int srow = t >> 3, scol = (t & 7) << 3;
#pragma unroll
    for (int i = 0; i < 8; ++i)
        gload16(KQ + (row0 + srow + i * 32) * E_ + h * 64 + scol, kqs + i * 2048 + t * 8);

    const float* kvg = KV + bh * 4096;
#pragma unroll
    for (int ii = 0; ii < 16; ii += 4) {
        float4 v = *(const float4*)(kvg + t * 16 + ii);
        u16x4 o; o[0] = f2b(v.x); o[1] = f2b(v.y); o[2] = f2b(v.z); o[3] = f2b(v.w);
        *(u16x4*)&bsm[t * 16 + ii] = o;
    }
    if (t < 64) bsm[4096 + t] = f2b(KSUM[bh * 64 + t]);
    for (int i = t; i < 960; i += 256) bsm[4160 + i] = 0;
    __syncthreads();

    f32x4 acc[4][5] = {};
#pragma unroll
    for (int kh = 0; kh < 2; ++kh) {
        int ko = kh * 32 + lg * 8;
        bf16x8 af[4];
#pragma unroll
        for (int mi = 0; mi < 4; ++mi)
            af[mi] = *(const bf16x8*)&kqs[(w * 64 + mi * 16 + lr) * 64 + ko];
#pragma unroll
        for (int ni = 0; ni < 5; ++ni) {
            bf16x8 bb = *(const bf16x8*)&bsm[(ni * 16 + lr) * 64 + ko];
#pragma unroll
            for (int mi = 0; mi < 4; ++mi)
                acc[mi][ni] = __builtin_amdgcn_mfma_f32_16x16x32_bf16(af[mi], bb, acc[mi][ni], 0, 0, 0);
        }
    }
    if (lr == 0) {
#pragma unroll
        for (int mi = 0; mi < 4; ++mi)
#pragma unroll
            for (int j = 0; j < 4; ++j)
                den[w * 64 + mi * 16 + lg * 4 + j] = acc[mi][4][j];
    }
    __syncthreads();
#pragma unroll
    for (int mi = 0; mi < 4; ++mi)
#pragma unroll
        for (int j = 0; j < 4; ++j) {
            int sl = w * 64 + mi * 16 + lg * 4 + j;
            float z = 1.f / (den[sl] + 1e-6f);
            float* op = Out + (row0 + sl) * E_ + h * 64;
#pragma unroll
            for (int ni = 0; ni < 4; ++ni)
                op[ni * 16 + lr] = acc[mi][ni][j] * z;
        }
}

extern "C" void kernel_launch(void* const* d_in, const int* in_sizes, int n_in,
                              void* d_out, int out_size, void* d_ws, size_t ws_size,
                              hipStream_t stream)
{
    const float* inputs = (const float*)d_in[0];
    const float* mask   = (const float*)d_in[1];
    const float* w_qkv  = (const float*)d_in[2];
    const float* b_qkv  = (const float*)d_in[3];

    u16* Abf = (u16*)d_ws;                      // 16777216 bf16
    u16* Wbf = Abf + (size_t)M_ * K_;           // 3145728 bf16
    u16* KQ  = Wbf + (size_t)N_ * K_;           // 16777216 bf16
    float* KVP  = (float*)(KQ + (size_t)M_ * E_);   // 16*262144 f32
    float* KSP  = KVP + 16 * 64 * 4096;             // 16*4096 f32
    float* KV   = KSP + 16 * 4096;                  // 262144 f32
    float* KSUM = KV + 64 * 4096;                   // 4096 f32

    // V^T lives in d_out (bf16, 33.5 MB); each block reads back only what it
    // wrote (self-contained); attn_out overwrites d_out with fp32 output last.
    u16* VT = (u16*)d_out;

    cvt_bf16<<<2048, 256, 0, stream>>>(inputs, Abf, M_ * K_ / 8);
    cvt_bf16<<<768, 256, 0, stream>>>(w_qkv, Wbf, N_ * K_ / 8);
    gemm_fused<<<256, 512, 0, stream>>>(Abf, Wbf, b_qkv, mask, KQ, VT, KVP, KSP);
    reduce_kv<<<256, 256, 0, stream>>>(KVP, KSP, KV, KSUM);
    attn_out<<<dim3(64, 16), 256, 0, stream>>>(KQ, KV, KSUM, (float*)d_out);
}